// Round 5
// baseline (634.999 us; speedup 1.0000x reference)
//
#include <hip/hip_runtime.h>

#define FDIM 128
typedef float v2f __attribute__((ext_vector_type(2)));
typedef float v4f __attribute__((ext_vector_type(4)));
typedef unsigned long long u64;
typedef unsigned int u32;

// bucket = row >> 7  (128 rows per bucket); col must fit 17 bits (N<=131072)
#define BSHIFT 7
#define BROWS 128

static __device__ inline unsigned short f2bf(float f) {
    u32 u = __float_as_uint(f);
    u32 r = (u + 0x7fffu + ((u >> 16) & 1u)) >> 16;   // RTN-even
    return (unsigned short)r;
}

// ---------------------------------------------------------------------------
// Pass A: per-bucket edge histogram (LDS-aggregated)
// ---------------------------------------------------------------------------
__global__ __launch_bounds__(256) void bucket_hist(
    const int* __restrict__ row, int* __restrict__ gcnt, int nedges, int nb)
{
    __shared__ int h[1024];
    const int tid = threadIdx.x;
    for (int i = tid; i < nb; i += 256) h[i] = 0;
    __syncthreads();

    int n4 = nedges >> 2;
    int stride = gridDim.x * 256;
    for (int i = blockIdx.x * 256 + tid; i < n4; i += stride) {
        int4 r = *reinterpret_cast<const int4*>(row + i * 4);
        atomicAdd(&h[r.x >> BSHIFT], 1);
        atomicAdd(&h[r.y >> BSHIFT], 1);
        atomicAdd(&h[r.z >> BSHIFT], 1);
        atomicAdd(&h[r.w >> BSHIFT], 1);
    }
    // tail
    if (blockIdx.x == 0)
        for (int e = n4 * 4 + tid; e < nedges; e += 256)
            atomicAdd(&h[row[e] >> BSHIFT], 1);
    __syncthreads();
    for (int i = tid; i < nb; i += 256)
        if (h[i]) atomicAdd(&gcnt[i], h[i]);
}

// ---------------------------------------------------------------------------
// Pass B: exclusive scan of bucket counts (single block). Writes bbase[0..nb]
// (bbase[nb]=E) and gcur[0..nb-1] (= start cursors for pass C).
// ---------------------------------------------------------------------------
__global__ __launch_bounds__(1024) void bucket_scan(
    const int* __restrict__ gcnt, int* __restrict__ bbase,
    int* __restrict__ gcur, int nb)
{
    __shared__ int s[1024];
    const int tid = threadIdx.x;
    int v = (tid < nb) ? gcnt[tid] : 0;
    s[tid] = v;
    __syncthreads();
    #pragma unroll
    for (int off = 1; off < 1024; off <<= 1) {
        int add = (tid >= off) ? s[tid - off] : 0;
        __syncthreads();
        s[tid] += add;
        __syncthreads();
    }
    if (tid < nb) {
        int excl = s[tid] - v;
        bbase[tid] = excl;
        gcur[tid]  = excl;
        if (tid == nb - 1) bbase[nb] = s[tid];   // total = E
    }
}

// ---------------------------------------------------------------------------
// Pass C: partition edges into buckets. Appends cluster to bucket tails ->
// lines fill contiguously in L2 (low write amplification).
// pk = [val:63..32 | localrow:23..17 | col:16..0]
// ---------------------------------------------------------------------------
__global__ __launch_bounds__(256) void partition(
    const int* __restrict__ row, const int* __restrict__ col,
    const float* __restrict__ val, int* __restrict__ gcur,
    u64* __restrict__ part, int nedges)
{
    int e = blockIdx.x * 256 + threadIdx.x;
    if (e < nedges) {
        int r = row[e];
        int b = r >> BSHIFT;
        int slot = atomicAdd(&gcur[b], 1);
        u64 pk = ((u64)__float_as_uint(val[e]) << 32) |
                 ((u64)(r & (BROWS - 1)) << 17) | (u32)col[e];
        part[slot] = pk;
    }
}

// ---------------------------------------------------------------------------
// Pass D: per-bucket CSR build. One block per bucket: LDS hist(128) ->
// LDS scan -> scatter into the bucket's slice of epack (L2-resident window).
// rowptr[r] ends up as END pointer (start = rowptr[r-1]).
// ---------------------------------------------------------------------------
__global__ __launch_bounds__(256) void bucket_csr(
    const u64* __restrict__ part, const int* __restrict__ bbase,
    u64* __restrict__ epack, int* __restrict__ rowptr, int M)
{
    __shared__ int hist[BROWS];
    __shared__ int cur[BROWS];
    const int tid  = threadIdx.x;
    const int b    = blockIdx.x;
    const int base = bbase[b];
    const int endS = bbase[b + 1];

    if (tid < BROWS) hist[tid] = 0;
    __syncthreads();

    for (int i = base + tid; i < endS; i += 256) {
        int lr = (int)((part[i] >> 17) & (BROWS - 1));
        atomicAdd(&hist[lr], 1);
    }
    __syncthreads();

    // exclusive scan of hist[0..127] (Hillis-Steele, uniform syncs)
    int v = (tid < BROWS) ? hist[tid] : 0;
    if (tid < BROWS) cur[tid] = v;
    __syncthreads();
    #pragma unroll
    for (int off = 1; off < BROWS; off <<= 1) {
        int add = (tid >= off && tid < BROWS) ? cur[tid - off] : 0;
        __syncthreads();
        if (tid < BROWS) cur[tid] += add;
        __syncthreads();
    }
    if (tid < BROWS) cur[tid] = base + cur[tid] - v;   // start offsets
    __syncthreads();

    for (int i = base + tid; i < endS; i += 256) {
        u64 p  = part[i];
        int lr = (int)((p >> 17) & (BROWS - 1));
        int slot = atomicAdd(&cur[lr], 1);
        epack[slot] = ((p >> 32) << 32) | (p & 0x1ffffu);  // [val|col]
    }
    __syncthreads();

    if (tid < BROWS) {
        int rg = b * BROWS + tid;
        if (rg < M) rowptr[rg] = cur[tid];   // == end pointer
    }
}

// ---------------------------------------------------------------------------
// SpMM (CSR gather, bf16 y): out[r] = sum_e val[e] * y[col[e]]
// One wave per row; halves process 2 edges concurrently; lane owns 4 feats
// (bf16x4 = 8B gather); cross-half shfl_xor reduce; lanes<32 write f32x4.
// ---------------------------------------------------------------------------
__global__ __launch_bounds__(256) void spmm_bf16(
    const int* __restrict__ rowptr, const u64* __restrict__ epack,
    const unsigned short* __restrict__ ybf, float* __restrict__ out, int M)
{
    const int row = blockIdx.x * 4 + (threadIdx.x >> 6);
    if (row >= M) return;
    const int lane = threadIdx.x & 63;
    const int h    = lane >> 5;          // 0/1: which edge of the pair
    const int hl   = lane & 31;          // feature group: feats hl*4..hl*4+3

    const int start = (row == 0) ? 0 : rowptr[row - 1];
    const int end   = rowptr[row];

    float a0 = 0.f, a1 = 0.f, a2 = 0.f, a3 = 0.f;

    int j = start;
    // 4 edges (2 pairs) per iteration: two independent gathers per half
    for (; j + 4 <= end; j += 4) {
        u64 p0 = epack[j + h];
        u64 p1 = epack[j + 2 + h];
        const ushort4* q0 = reinterpret_cast<const ushort4*>(
            ybf + (size_t)(u32)(p0 & 0x1ffffu) * FDIM + hl * 4);
        const ushort4* q1 = reinterpret_cast<const ushort4*>(
            ybf + (size_t)(u32)(p1 & 0x1ffffu) * FDIM + hl * 4);
        ushort4 y0 = *q0;
        ushort4 y1 = *q1;
        float v0 = __uint_as_float((u32)(p0 >> 32));
        float v1 = __uint_as_float((u32)(p1 >> 32));
        a0 = fmaf(v0, __uint_as_float((u32)y0.x << 16), a0);
        a1 = fmaf(v0, __uint_as_float((u32)y0.y << 16), a1);
        a2 = fmaf(v0, __uint_as_float((u32)y0.z << 16), a2);
        a3 = fmaf(v0, __uint_as_float((u32)y0.w << 16), a3);
        a0 = fmaf(v1, __uint_as_float((u32)y1.x << 16), a0);
        a1 = fmaf(v1, __uint_as_float((u32)y1.y << 16), a1);
        a2 = fmaf(v1, __uint_as_float((u32)y1.z << 16), a2);
        a3 = fmaf(v1, __uint_as_float((u32)y1.w << 16), a3);
    }
    // remainder (0..3 edges), masked
    for (; j < end; j += 2) {
        int jj = j + h;
        u64 p0 = (jj < end) ? epack[jj] : 0ull;   // v=0, col=0: harmless
        ushort4 y0 = *reinterpret_cast<const ushort4*>(
            ybf + (size_t)(u32)(p0 & 0x1ffffu) * FDIM + hl * 4);
        float v0 = __uint_as_float((u32)(p0 >> 32));
        a0 = fmaf(v0, __uint_as_float((u32)y0.x << 16), a0);
        a1 = fmaf(v0, __uint_as_float((u32)y0.y << 16), a1);
        a2 = fmaf(v0, __uint_as_float((u32)y0.z << 16), a2);
        a3 = fmaf(v0, __uint_as_float((u32)y0.w << 16), a3);
    }

    // cross-half reduce (edge-even + edge-odd partials)
    a0 += __shfl_xor(a0, 32);
    a1 += __shfl_xor(a1, 32);
    a2 += __shfl_xor(a2, 32);
    a3 += __shfl_xor(a3, 32);

    if (h == 0) {
        v4f acc = {a0, a1, a2, a3};
        __builtin_nontemporal_store(
            acc, reinterpret_cast<v4f*>(out + (size_t)row * FDIM + hl * 4));
    }
}

// ---------------------------------------------------------------------------
// GEMM: y_bf16[M,128] = x[M,128] @ W[128,128]  (fp32 vector ALU, bf16 store)
// ---------------------------------------------------------------------------
__global__ __launch_bounds__(256, 2) void gemm_xw(
    const float* __restrict__ x, const float* __restrict__ w,
    unsigned short* __restrict__ y, int M)
{
    __shared__ float sZt[128 * 65];
    __shared__ float sW[64 * 132];

    const int tidx = threadIdx.x;
    const int rowBase = blockIdx.x * 64;

    #pragma unroll
    for (int i = 0; i < 8; ++i) {
        int idx = tidx + 256 * i;
        int r   = idx >> 5;
        int k4  = idx & 31;
        float4 v = make_float4(0.f, 0.f, 0.f, 0.f);
        if (rowBase + r < M)
            v = *reinterpret_cast<const float4*>(
                x + (size_t)(rowBase + r) * FDIM + k4 * 4);
        sZt[(k4 * 4 + 0) * 65 + r] = v.x;
        sZt[(k4 * 4 + 1) * 65 + r] = v.y;
        sZt[(k4 * 4 + 2) * 65 + r] = v.z;
        sZt[(k4 * 4 + 3) * 65 + r] = v.w;
    }

    const int ty = tidx >> 4;
    const int tx = tidx & 15;
    const int r0 = ty * 4;
    const int c0 = tx * 4;

    float acc[4][8] = {};

    for (int kc = 0; kc < 128; kc += 64) {
        __syncthreads();
        #pragma unroll
        for (int i = 0; i < 8; ++i) {
            int idx = tidx + 256 * i;
            int k   = idx >> 5;
            int c4  = idx & 31;
            float4 v = *reinterpret_cast<const float4*>(
                w + (size_t)(kc + k) * FDIM + c4 * 4);
            *reinterpret_cast<float4*>(&sW[k * 132 + c4 * 4]) = v;
        }
        __syncthreads();

        #pragma unroll 8
        for (int kk = 0; kk < 64; ++kk) {
            int k = kc + kk;
            float4 zv = *reinterpret_cast<const float4*>(&sZt[k * 65 + r0]);
            float4 w0 = *reinterpret_cast<const float4*>(&sW[kk * 132 + c0]);
            float4 w1 = *reinterpret_cast<const float4*>(&sW[kk * 132 + c0 + 64]);
            float zr[4] = {zv.x, zv.y, zv.z, zv.w};
            float wv[8] = {w0.x, w0.y, w0.z, w0.w, w1.x, w1.y, w1.z, w1.w};
            #pragma unroll
            for (int i = 0; i < 4; ++i)
                #pragma unroll
                for (int j = 0; j < 8; ++j)
                    acc[i][j] += zr[i] * wv[j];
        }
    }

    #pragma unroll
    for (int i = 0; i < 4; ++i) {
        int r = rowBase + r0 + i;
        if (r < M) {
            ushort4 o0 = {f2bf(acc[i][0]), f2bf(acc[i][1]),
                          f2bf(acc[i][2]), f2bf(acc[i][3])};
            ushort4 o1 = {f2bf(acc[i][4]), f2bf(acc[i][5]),
                          f2bf(acc[i][6]), f2bf(acc[i][7])};
            *reinterpret_cast<ushort4*>(y + (size_t)r * FDIM + c0)      = o0;
            *reinterpret_cast<ushort4*>(y + (size_t)r * FDIM + c0 + 64) = o1;
        }
    }
}

extern "C" void kernel_launch(void* const* d_in, const int* in_sizes, int n_in,
                              void* d_out, int out_size, void* d_ws, size_t ws_size,
                              hipStream_t stream) {
    const int*   row = (const int*)d_in[0];
    const int*   col = (const int*)d_in[1];
    const float* val = (const float*)d_in[2];
    const float* x   = (const float*)d_in[3];
    const float* w   = (const float*)d_in[4];
    float* out = (float*)d_out;

    const int E  = in_sizes[0];
    const int M  = in_sizes[3] / FDIM;            // 100000
    const int NB = (M + BROWS - 1) >> BSHIFT;     // 782 buckets (<=1023)

    char* ws = (char*)d_ws;
    size_t off = 0;
    auto carve = [&](size_t bytes) {
        void* p = ws + off;
        off += (bytes + 255) & ~(size_t)255;
        return p;
    };
    unsigned short* ybf    = (unsigned short*)carve((size_t)M * FDIM * 2);
    u64*            part   = (u64*)carve((size_t)E * 8);
    u64*            epack  = (u64*)carve((size_t)E * 8);
    int*            rowptr = (int*)carve((size_t)M * sizeof(int));
    int*            gcnt   = (int*)carve(1024 * sizeof(int));
    int*            bbase  = (int*)carve(1025 * sizeof(int));
    int*            gcur   = (int*)carve(1024 * sizeof(int));

    // y = x @ W  -> bf16 (independent of CSR build)
    gemm_xw<<<(M + 63) / 64, 256, 0, stream>>>(x, w, ybf, M);

    hipMemsetAsync(gcnt, 0, (size_t)NB * sizeof(int), stream);
    bucket_hist<<<512, 256, 0, stream>>>(row, gcnt, E, NB);
    bucket_scan<<<1, 1024, 0, stream>>>(gcnt, bbase, gcur, NB);
    partition<<<(E + 255) / 256, 256, 0, stream>>>(row, col, val, gcur,
                                                   part, E);
    bucket_csr<<<NB, 256, 0, stream>>>(part, bbase, epack, rowptr, M);

    // out = A @ y
    spmm_bf16<<<(M + 3) / 4, 256, 0, stream>>>(rowptr, epack, ybf, out, M);
}

// Round 6
// 308.007 us; speedup vs baseline: 2.0616x; 2.0616x over previous
//
#include <hip/hip_runtime.h>

#define FDIM 128
typedef float v4f __attribute__((ext_vector_type(4)));
typedef unsigned long long u64;
typedef unsigned int u32;

// bucket = row >> 7  (128 rows per bucket); col fits 17 bits (N<=131072)
#define BSHIFT 7
#define BROWS 128
#define NBMAX 1024
#define CHUNK 8192   // edges per partition block

static __device__ inline unsigned short f2bf(float f) {
    u32 u = __float_as_uint(f);
    u32 r = (u + 0x7fffu + ((u >> 16) & 1u)) >> 16;   // RTN-even
    return (unsigned short)r;
}

// ---------------------------------------------------------------------------
// Pass A: per-bucket edge histogram (LDS-aggregated)
// ---------------------------------------------------------------------------
__global__ __launch_bounds__(256) void bucket_hist(
    const int* __restrict__ row, int* __restrict__ gcnt, int nedges, int nb)
{
    __shared__ int h[NBMAX];
    const int tid = threadIdx.x;
    for (int i = tid; i < nb; i += 256) h[i] = 0;
    __syncthreads();

    int n4 = nedges >> 2;
    int stride = gridDim.x * 256;
    for (int i = blockIdx.x * 256 + tid; i < n4; i += stride) {
        int4 r = *reinterpret_cast<const int4*>(row + i * 4);
        atomicAdd(&h[r.x >> BSHIFT], 1);
        atomicAdd(&h[r.y >> BSHIFT], 1);
        atomicAdd(&h[r.z >> BSHIFT], 1);
        atomicAdd(&h[r.w >> BSHIFT], 1);
    }
    if (blockIdx.x == 0)
        for (int e = n4 * 4 + tid; e < nedges; e += 256)
            atomicAdd(&h[row[e] >> BSHIFT], 1);
    __syncthreads();
    for (int i = tid; i < nb; i += 256)
        if (h[i]) atomicAdd(&gcnt[i], h[i]);
}

// ---------------------------------------------------------------------------
// Pass B: exclusive scan of bucket counts (single block).
// bbase[0..nb] (bbase[nb]=E); gcur[i] = start cursor for partition.
// ---------------------------------------------------------------------------
__global__ __launch_bounds__(1024) void bucket_scan(
    const int* __restrict__ gcnt, int* __restrict__ bbase,
    int* __restrict__ gcur, int nb)
{
    __shared__ int s[1024];
    const int tid = threadIdx.x;
    int v = (tid < nb) ? gcnt[tid] : 0;
    s[tid] = v;
    __syncthreads();
    #pragma unroll
    for (int off = 1; off < 1024; off <<= 1) {
        int add = (tid >= off) ? s[tid - off] : 0;
        __syncthreads();
        s[tid] += add;
        __syncthreads();
    }
    if (tid < nb) {
        int excl = s[tid] - v;
        bbase[tid] = excl;
        gcur[tid]  = excl;
        if (tid == nb - 1) bbase[nb] = s[tid];
    }
}

// ---------------------------------------------------------------------------
// Pass C: CHUNKED partition. Per block: LDS hist over its 8192-edge chunk,
// ONE global atomicAdd per touched bucket to reserve a contiguous run, then
// scatter via LDS cursors. Global atomics: ~(E/CHUNK)*nb ~= 153K (vs 1.6M).
// pk = [val:63..32 | localrow:23..17 | col:16..0]
// ---------------------------------------------------------------------------
__global__ __launch_bounds__(256) void partition2(
    const int* __restrict__ row, const int* __restrict__ col,
    const float* __restrict__ val, int* __restrict__ gcur,
    u64* __restrict__ part, int nedges, int nb)
{
    __shared__ int hist[NBMAX];   // pass1: counts; pass2: local cursor
    __shared__ int rbase[NBMAX];  // reserved global base per bucket
    const int tid = threadIdx.x;
    const int e0  = blockIdx.x * CHUNK;
    const int e1  = min(e0 + CHUNK, nedges);

    for (int i = tid; i < nb; i += 256) hist[i] = 0;
    __syncthreads();

    for (int e = e0 + tid; e < e1; e += 256)
        atomicAdd(&hist[row[e] >> BSHIFT], 1);
    __syncthreads();

    for (int i = tid; i < nb; i += 256) {
        int c = hist[i];
        rbase[i] = c ? atomicAdd(&gcur[i], c) : 0;
        hist[i] = 0;                      // reuse as local cursor
    }
    __syncthreads();

    for (int e = e0 + tid; e < e1; e += 256) {
        int r = row[e];
        int b = r >> BSHIFT;
        int slot = rbase[b] + atomicAdd(&hist[b], 1);
        u64 pk = ((u64)__float_as_uint(val[e]) << 32) |
                 ((u64)(r & (BROWS - 1)) << 17) | (u32)col[e];
        part[slot] = pk;
    }
}

// ---------------------------------------------------------------------------
// Pass D: per-bucket CSR build (one block per bucket, L2-resident window).
// rowptr[r] ends as END pointer (start = rowptr[r-1]).
// ---------------------------------------------------------------------------
__global__ __launch_bounds__(256) void bucket_csr(
    const u64* __restrict__ part, const int* __restrict__ bbase,
    u64* __restrict__ epack, int* __restrict__ rowptr, int M)
{
    __shared__ int hist[BROWS];
    __shared__ int cur[BROWS];
    const int tid  = threadIdx.x;
    const int b    = blockIdx.x;
    const int base = bbase[b];
    const int endS = bbase[b + 1];

    if (tid < BROWS) hist[tid] = 0;
    __syncthreads();

    for (int i = base + tid; i < endS; i += 256) {
        int lr = (int)((part[i] >> 17) & (BROWS - 1));
        atomicAdd(&hist[lr], 1);
    }
    __syncthreads();

    int v = (tid < BROWS) ? hist[tid] : 0;
    if (tid < BROWS) cur[tid] = v;
    __syncthreads();
    #pragma unroll
    for (int off = 1; off < BROWS; off <<= 1) {
        int add = (tid >= off && tid < BROWS) ? cur[tid - off] : 0;
        __syncthreads();
        if (tid < BROWS) cur[tid] += add;
        __syncthreads();
    }
    if (tid < BROWS) cur[tid] = base + cur[tid] - v;
    __syncthreads();

    for (int i = base + tid; i < endS; i += 256) {
        u64 p  = part[i];
        int lr = (int)((p >> 17) & (BROWS - 1));
        int slot = atomicAdd(&cur[lr], 1);
        epack[slot] = ((p >> 32) << 32) | (p & 0x1ffffu);  // [val|col]
    }
    __syncthreads();

    if (tid < BROWS) {
        int rg = b * BROWS + tid;
        if (rg < M) rowptr[rg] = cur[tid];
    }
}

// ---------------------------------------------------------------------------
// SpMM (CSR gather, bf16 y): out[r] = sum_e val[e] * y[col[e]]
// One wave per row; halves process 2 edges concurrently; lane owns 4 feats.
// ---------------------------------------------------------------------------
__global__ __launch_bounds__(256) void spmm_bf16(
    const int* __restrict__ rowptr, const u64* __restrict__ epack,
    const unsigned short* __restrict__ ybf, float* __restrict__ out, int M)
{
    const int row = blockIdx.x * 4 + (threadIdx.x >> 6);
    if (row >= M) return;
    const int lane = threadIdx.x & 63;
    const int h    = lane >> 5;
    const int hl   = lane & 31;

    const int start = (row == 0) ? 0 : rowptr[row - 1];
    const int end   = rowptr[row];

    float a0 = 0.f, a1 = 0.f, a2 = 0.f, a3 = 0.f;

    int j = start;
    for (; j + 4 <= end; j += 4) {
        u64 p0 = epack[j + h];
        u64 p1 = epack[j + 2 + h];
        ushort4 y0 = *reinterpret_cast<const ushort4*>(
            ybf + (size_t)(u32)(p0 & 0x1ffffu) * FDIM + hl * 4);
        ushort4 y1 = *reinterpret_cast<const ushort4*>(
            ybf + (size_t)(u32)(p1 & 0x1ffffu) * FDIM + hl * 4);
        float v0 = __uint_as_float((u32)(p0 >> 32));
        float v1 = __uint_as_float((u32)(p1 >> 32));
        a0 = fmaf(v0, __uint_as_float((u32)y0.x << 16), a0);
        a1 = fmaf(v0, __uint_as_float((u32)y0.y << 16), a1);
        a2 = fmaf(v0, __uint_as_float((u32)y0.z << 16), a2);
        a3 = fmaf(v0, __uint_as_float((u32)y0.w << 16), a3);
        a0 = fmaf(v1, __uint_as_float((u32)y1.x << 16), a0);
        a1 = fmaf(v1, __uint_as_float((u32)y1.y << 16), a1);
        a2 = fmaf(v1, __uint_as_float((u32)y1.z << 16), a2);
        a3 = fmaf(v1, __uint_as_float((u32)y1.w << 16), a3);
    }
    for (; j < end; j += 2) {
        int jj = j + h;
        u64 p0 = (jj < end) ? epack[jj] : 0ull;
        ushort4 y0 = *reinterpret_cast<const ushort4*>(
            ybf + (size_t)(u32)(p0 & 0x1ffffu) * FDIM + hl * 4);
        float v0 = __uint_as_float((u32)(p0 >> 32));
        a0 = fmaf(v0, __uint_as_float((u32)y0.x << 16), a0);
        a1 = fmaf(v0, __uint_as_float((u32)y0.y << 16), a1);
        a2 = fmaf(v0, __uint_as_float((u32)y0.z << 16), a2);
        a3 = fmaf(v0, __uint_as_float((u32)y0.w << 16), a3);
    }

    a0 += __shfl_xor(a0, 32);
    a1 += __shfl_xor(a1, 32);
    a2 += __shfl_xor(a2, 32);
    a3 += __shfl_xor(a3, 32);

    if (h == 0) {
        v4f acc = {a0, a1, a2, a3};
        __builtin_nontemporal_store(
            acc, reinterpret_cast<v4f*>(out + (size_t)row * FDIM + hl * 4));
    }
}

// ---------------------------------------------------------------------------
// GEMM: y_bf16[M,128] = x[M,128] @ W[128,128]  (fp32 vector ALU, bf16 store)
// ---------------------------------------------------------------------------
__global__ __launch_bounds__(256, 2) void gemm_xw(
    const float* __restrict__ x, const float* __restrict__ w,
    unsigned short* __restrict__ y, int M)
{
    __shared__ float sZt[128 * 65];
    __shared__ float sW[64 * 132];

    const int tidx = threadIdx.x;
    const int rowBase = blockIdx.x * 64;

    #pragma unroll
    for (int i = 0; i < 8; ++i) {
        int idx = tidx + 256 * i;
        int r   = idx >> 5;
        int k4  = idx & 31;
        float4 v = make_float4(0.f, 0.f, 0.f, 0.f);
        if (rowBase + r < M)
            v = *reinterpret_cast<const float4*>(
                x + (size_t)(rowBase + r) * FDIM + k4 * 4);
        sZt[(k4 * 4 + 0) * 65 + r] = v.x;
        sZt[(k4 * 4 + 1) * 65 + r] = v.y;
        sZt[(k4 * 4 + 2) * 65 + r] = v.z;
        sZt[(k4 * 4 + 3) * 65 + r] = v.w;
    }

    const int ty = tidx >> 4;
    const int tx = tidx & 15;
    const int r0 = ty * 4;
    const int c0 = tx * 4;

    float acc[4][8] = {};

    for (int kc = 0; kc < 128; kc += 64) {
        __syncthreads();
        #pragma unroll
        for (int i = 0; i < 8; ++i) {
            int idx = tidx + 256 * i;
            int k   = idx >> 5;
            int c4  = idx & 31;
            float4 v = *reinterpret_cast<const float4*>(
                w + (size_t)(kc + k) * FDIM + c4 * 4);
            *reinterpret_cast<float4*>(&sW[k * 132 + c4 * 4]) = v;
        }
        __syncthreads();

        #pragma unroll 8
        for (int kk = 0; kk < 64; ++kk) {
            int k = kc + kk;
            float4 zv = *reinterpret_cast<const float4*>(&sZt[k * 65 + r0]);
            float4 w0 = *reinterpret_cast<const float4*>(&sW[kk * 132 + c0]);
            float4 w1 = *reinterpret_cast<const float4*>(&sW[kk * 132 + c0 + 64]);
            float zr[4] = {zv.x, zv.y, zv.z, zv.w};
            float wv[8] = {w0.x, w0.y, w0.z, w0.w, w1.x, w1.y, w1.z, w1.w};
            #pragma unroll
            for (int i = 0; i < 4; ++i)
                #pragma unroll
                for (int j = 0; j < 8; ++j)
                    acc[i][j] += zr[i] * wv[j];
        }
    }

    #pragma unroll
    for (int i = 0; i < 4; ++i) {
        int r = rowBase + r0 + i;
        if (r < M) {
            ushort4 o0 = {f2bf(acc[i][0]), f2bf(acc[i][1]),
                          f2bf(acc[i][2]), f2bf(acc[i][3])};
            ushort4 o1 = {f2bf(acc[i][4]), f2bf(acc[i][5]),
                          f2bf(acc[i][6]), f2bf(acc[i][7])};
            *reinterpret_cast<ushort4*>(y + (size_t)r * FDIM + c0)      = o0;
            *reinterpret_cast<ushort4*>(y + (size_t)r * FDIM + c0 + 64) = o1;
        }
    }
}

extern "C" void kernel_launch(void* const* d_in, const int* in_sizes, int n_in,
                              void* d_out, int out_size, void* d_ws, size_t ws_size,
                              hipStream_t stream) {
    const int*   row = (const int*)d_in[0];
    const int*   col = (const int*)d_in[1];
    const float* val = (const float*)d_in[2];
    const float* x   = (const float*)d_in[3];
    const float* w   = (const float*)d_in[4];
    float* out = (float*)d_out;

    const int E  = in_sizes[0];
    const int M  = in_sizes[3] / FDIM;            // 100000
    const int NB = (M + BROWS - 1) >> BSHIFT;     // 782 buckets

    char* ws = (char*)d_ws;
    size_t off = 0;
    auto carve = [&](size_t bytes) {
        void* p = ws + off;
        off += (bytes + 255) & ~(size_t)255;
        return p;
    };
    unsigned short* ybf    = (unsigned short*)carve((size_t)M * FDIM * 2);
    u64*            part   = (u64*)carve((size_t)E * 8);
    u64*            epack  = (u64*)carve((size_t)E * 8);
    int*            rowptr = (int*)carve((size_t)M * sizeof(int));
    int*            gcnt   = (int*)carve(NBMAX * sizeof(int));
    int*            bbase  = (int*)carve((NBMAX + 1) * sizeof(int));
    int*            gcur   = (int*)carve(NBMAX * sizeof(int));

    // y = x @ W  -> bf16 (independent of CSR build)
    gemm_xw<<<(M + 63) / 64, 256, 0, stream>>>(x, w, ybf, M);

    hipMemsetAsync(gcnt, 0, (size_t)NB * sizeof(int), stream);
    bucket_hist<<<512, 256, 0, stream>>>(row, gcnt, E, NB);
    bucket_scan<<<1, 1024, 0, stream>>>(gcnt, bbase, gcur, NB);
    partition2<<<(E + CHUNK - 1) / CHUNK, 256, 0, stream>>>(
        row, col, val, gcur, part, E, NB);
    bucket_csr<<<NB, 256, 0, stream>>>(part, bbase, epack, rowptr, M);

    // out = A @ y
    spmm_bf16<<<(M + 3) / 4, 256, 0, stream>>>(rowptr, epack, ybf, out, M);
}